// Round 5
// baseline (1079.355 us; speedup 1.0000x reference)
//
#include <hip/hip_runtime.h>
#include <math.h>

#define T_ 4096
#define D_ 512
#define H_ 1024
#define E_ 8
#define Q_ 4

typedef _Float16 h8 __attribute__((ext_vector_type(8)));
typedef float f4 __attribute__((ext_vector_type(4)));

__device__ __forceinline__ float gelu_exact(float v){
    return 0.5f * v * (1.0f + erff(v * 0.70710678118654752440f));
}
__device__ __forceinline__ float sigm(float v){
    return 1.0f / (1.0f + expf(-v));
}

// ---------------------------------------------------------------------------
// Router level (16 tokens/block): hidden(256)=gelu(x@w1+b1) -> LN -> logits
// ---------------------------------------------------------------------------
template<int OUTL>
__device__ void router_level16(
    const float* __restrict__ xg,
    const float* __restrict__ w1, const float* __restrict__ b1,
    const float* __restrict__ g,  const float* __restrict__ be,
    const float* __restrict__ w2, const float* __restrict__ b2,
    float* __restrict__ Hl,     // [16][264]
    float* __restrict__ logit,  // [16][8]
    float* __restrict__ mrs,    // [16][2]
    float* __restrict__ red,    // >= 4160
    int tid)
{
    float acc[16];
#pragma unroll
    for (int t=0;t<16;++t) acc[t]=0.f;
    const float bb = b1[tid];
    {
        float wpf[8];
#pragma unroll
        for (int p=0;p<8;++p) wpf[p] = w1[p*256 + tid];
#pragma unroll 8
        for (int d=0; d<504; ++d){
            const int s = d & 7;
            const float w = wpf[s];
            wpf[s] = w1[(d+8)*256 + tid];
#pragma unroll
            for (int t=0;t<16;++t) acc[t] = fmaf(xg[t*D_ + d], w, acc[t]);
        }
#pragma unroll
        for (int d=504; d<512; ++d){
            const float w = wpf[d & 7];
#pragma unroll
            for (int t=0;t<16;++t) acc[t] = fmaf(xg[t*D_ + d], w, acc[t]);
        }
    }
#pragma unroll
    for (int t=0;t<16;++t) Hl[t*264 + tid] = gelu_exact(acc[t] + bb);
    __syncthreads();

    // LayerNorm over 256: wave w handles tokens w*4..w*4+3
    {
        int wid = tid >> 6, lane = tid & 63;
#pragma unroll
        for (int tt=0; tt<4; ++tt){
            int t = wid*4 + tt;
            float s = Hl[t*264+lane] + Hl[t*264+lane+64] + Hl[t*264+lane+128] + Hl[t*264+lane+192];
#pragma unroll
            for (int o=1;o<64;o<<=1) s += __shfl_xor(s, o, 64);
            float m = s * (1.0f/256.0f);
            float v = 0.f;
#pragma unroll
            for (int r=0;r<4;++r){ float dd = Hl[t*264+lane+64*r] - m; v = fmaf(dd,dd,v); }
#pragma unroll
            for (int o=1;o<64;o<<=1) v += __shfl_xor(v, o, 64);
            if (lane==0){ mrs[t*2+0] = m; mrs[t*2+1] = rsqrtf(v*(1.0f/256.0f) + 1e-5f); }
        }
    }
    __syncthreads();
#pragma unroll
    for (int t=0;t<16;++t){
        float hv = Hl[t*264+tid];
        Hl[t*264+tid] = (hv - mrs[t*2]) * mrs[t*2+1] * g[tid] + be[tid];
    }
    __syncthreads();

    // logits: thread = (t=tid&15, kk=(tid>>4)&7, half=tid>>7), 128-j dot each
    {
        const int t = tid & 15, kk = (tid>>4) & 7, half = tid >> 7;
        const int col = kk & (OUTL-1);
        const float* w2q = w2 + (size_t)half*128*OUTL + col;
        const float* hq  = Hl + t*264 + half*128;
        float a = 0.f;
#pragma unroll 8
        for (int j=0;j<128;++j) a = fmaf(hq[j], w2q[j*OUTL], a);
        red[tid] = a;
    }
    __syncthreads();
    if (tid < 128){
        const int t = tid & 15, kk = tid >> 4;
        float s = red[tid] + red[tid+128] + b2[kk & (OUTL-1)];
        if (OUTL == 8) logit[t*8+kk] = s;
        else           logit[t*8+kk] += s;
    }
    __syncthreads();
}

// ---------------------------------------------------------------------------
// Kernel A: router + confidence + top2 + gating. 16 tokens/block, 256 blocks.
// ---------------------------------------------------------------------------
__global__ __launch_bounds__(256) void k_router(
    const float* __restrict__ x,
    const float* __restrict__ r0_w1, const float* __restrict__ r0_b1,
    const float* __restrict__ r0_g,  const float* __restrict__ r0_be,
    const float* __restrict__ r0_w2, const float* __restrict__ r0_b2,
    const float* __restrict__ r1_w1, const float* __restrict__ r1_b1,
    const float* __restrict__ r1_g,  const float* __restrict__ r1_be,
    const float* __restrict__ r1_w2, const float* __restrict__ r1_b2,
    const float* __restrict__ r2_w1, const float* __restrict__ r2_b1,
    const float* __restrict__ r2_g,  const float* __restrict__ r2_be,
    const float* __restrict__ r2_w2, const float* __restrict__ r2_b2,
    const float* __restrict__ cw1, const float* __restrict__ cb1,
    const float* __restrict__ cw2, const float* __restrict__ cb2,
    const float* __restrict__ gw, const float* __restrict__ gb,
    const float* __restrict__ ent,
    float* __restrict__ out_rw,
    float* __restrict__ wgt,
    int* __restrict__ selexp, int* __restrict__ listtok, int* __restrict__ listpr,
    int* __restrict__ counters, float* __restrict__ confsum)
{
    __shared__ float Xl[16*520];
    __shared__ float Hl[16*264];
    __shared__ float red[4160];
    __shared__ float h1c[1024];   // [16][64]
    __shared__ float logit[128];  // [16][8]
    __shared__ float rwl[128];    // [16][8]
    __shared__ float spl[512];    // [16][32]
    __shared__ float mrs[32];

    const int tid = threadIdx.x;
    const int tb  = blockIdx.x * 16;
    const float* xg = x + (size_t)tb * D_;
    {
        const float4* xv = (const float4*)xg;
#pragma unroll
        for (int r=0;r<8;++r){
            int i = r*256 + tid;            // 0..2047
            int t = i >> 7, c = i & 127;
            float4 v = xv[i];
            Xl[t*520 + c*4 + 0] = v.x;
            Xl[t*520 + c*4 + 1] = v.y;
            Xl[t*520 + c*4 + 2] = v.z;
            Xl[t*520 + c*4 + 3] = v.w;
        }
    }
    __syncthreads();

    // ---- confidence ----
    {
        int j = tid & 63, seg = tid >> 6;
        float a[16];
#pragma unroll
        for (int t=0;t<16;++t) a[t]=0.f;
        for (int d = seg*128; d < seg*128+128; ++d){
            float w = cw1[d*64 + j];
#pragma unroll
            for (int t=0;t<16;++t) a[t] = fmaf(Xl[t*520+d], w, a[t]);
        }
#pragma unroll
        for (int t=0;t<16;++t) red[t*257 + seg*64 + j] = a[t];
    }
    __syncthreads();
    if (tid < 64){
        int j = tid;
#pragma unroll
        for (int t=0;t<16;++t){
            float s = red[t*257+j] + red[t*257+64+j] + red[t*257+128+j] + red[t*257+192+j];
            h1c[t*64+j] = tanhf(s + cb1[j]);
        }
    }
    __syncthreads();
    if (tid < 16){
        float a = cb2[0];
        for (int j=0;j<64;++j) a = fmaf(h1c[tid*64+j], cw2[j], a);
        float c = sigm(a);
        atomicAdd(confsum, fabsf(c - 0.7f));
    }
    __syncthreads();

    router_level16<8>(xg, r0_w1,r0_b1,r0_g,r0_be,r0_w2,r0_b2, Hl, logit, mrs, red, tid);
    router_level16<4>(xg, r1_w1,r1_b1,r1_g,r1_be,r1_w2,r1_b2, Hl, logit, mrs, red, tid);
    router_level16<2>(xg, r2_w1,r2_b1,r2_g,r2_be,r2_w2,r2_b2, Hl, logit, mrs, red, tid);

    // ---- softmax + top2 + renorm + expert lists ----
    if (tid < 16){
        int t = tid;
        float l[8], p[8];
        float mx = -1e30f;
#pragma unroll
        for (int e=0;e<8;++e){ l[e]=logit[t*8+e]; mx = fmaxf(mx, l[e]); }
        float s=0.f;
#pragma unroll
        for (int e=0;e<8;++e){ p[e]=expf(l[e]-mx); s+=p[e]; }
        float inv = 1.f/s;
#pragma unroll
        for (int e=0;e<8;++e) p[e]*=inv;
        int i1=0; float v1=p[0];
#pragma unroll
        for (int e=1;e<8;++e) if (p[e] > v1){ v1=p[e]; i1=e; }
        int i2=-1; float v2=-1e30f;
#pragma unroll
        for (int e=0;e<8;++e) if (e!=i1 && p[e] > v2){ v2=p[e]; i2=e; }
        float denom = 1.f/(v1 + v2 + 1e-10f);
#pragma unroll
        for (int e=0;e<8;++e){
            float rv = (e==i1 || e==i2) ? p[e]*denom : 0.f;
            out_rw[(size_t)(tb+t)*8 + e] = rv;
            rwl[t*8+e] = rv;
        }
        selexp[(tb+t)*2+0] = i1;
        selexp[(tb+t)*2+1] = i2;
        int pos1 = atomicAdd(&counters[i1], 1);
        listtok[i1*T_+pos1] = tb+t; listpr[i1*T_+pos1] = (tb+t)*2;
        int pos2 = atomicAdd(&counters[i2], 1);
        listtok[i2*T_+pos2] = tb+t; listpr[i2*T_+pos2] = (tb+t)*2+1;
    }
    __syncthreads();

    // ---- gating: state_probs (2 tokens per thread, shared weight stream) ----
    {
        const int t0 = tid >> 5;              // 0..7
        const int eqq = tid & 31, e = eqq >> 2, q = eqq & 3;
        const float* gwp = gw + e*2048 + q;
        const float bias = gb[e*4+q];
        float a0 = bias, a1 = bias;
        float gpf[8];
#pragma unroll
        for (int p=0;p<8;++p) gpf[p] = gwp[p*4];
#pragma unroll 8
        for (int d=0; d<504; ++d){
            const int s = d & 7;
            const float w = gpf[s];
            gpf[s] = gwp[(d+8)*4];
            a0 = fmaf(Xl[t0*520+d], w, a0);
            a1 = fmaf(Xl[(t0+8)*520+d], w, a1);
        }
#pragma unroll
        for (int d=504; d<512; ++d){
            const float w = gpf[d&7];
            a0 = fmaf(Xl[t0*520+d], w, a0);
            a1 = fmaf(Xl[(t0+8)*520+d], w, a1);
        }
        spl[t0*32 + eqq] = a0;
        spl[(t0+8)*32 + eqq] = a1;
    }
    __syncthreads();
    if (tid < 128){
        int t = tid >> 3, e = tid & 7;
        float spv[4]; float mx=-1e30f;
#pragma unroll
        for (int q=0;q<4;++q){ spv[q]=spl[t*32+e*4+q]; mx=fmaxf(mx,spv[q]); }
        float ss=0.f;
#pragma unroll
        for (int q=0;q<4;++q){ spv[q]=expf(spv[q]-mx); ss+=spv[q]; }
        float inv=1.f/ss;
#pragma unroll
        for (int q=0;q<4;++q) spv[q]*=inv;
        float epv[4]; float mx2=-1e30f;
#pragma unroll
        for (int r=0;r<4;++r){
            float a = spv[0]*ent[e*16+r] + spv[1]*ent[e*16+4+r]
                    + spv[2]*ent[e*16+8+r] + spv[3]*ent[e*16+12+r];
            epv[r]=a; mx2=fmaxf(mx2,a);
        }
        float s2=0.f;
#pragma unroll
        for (int r=0;r<4;++r){ epv[r]=expf(epv[r]-mx2); s2+=epv[r]; }
        float inv2=1.f/s2;
        float rwv = rwl[t*8+e];
#pragma unroll
        for (int r=0;r<4;++r)
            wgt[((size_t)(tb+t)*E_ + e)*Q_ + r] = rwv * epv[r] * inv2;
    }
}

// ---------------------------------------------------------------------------
// Kernel B: b1_eff[e,q,h] = eb1[e,q,h] + sum_d emb[e,q,d]*ew1[e,q,d,h]
// ---------------------------------------------------------------------------
__global__ __launch_bounds__(128) void k_b1eff(
    const float* __restrict__ emb, const float* __restrict__ ew1,
    const float* __restrict__ eb1, float* __restrict__ b1eff)
{
    const int eq = blockIdx.x >> 3;
    const int hc = blockIdx.x & 7;
    __shared__ float el[512];
    const int tid = threadIdx.x;
    for (int i=tid;i<512;i+=128) el[i] = emb[eq*512+i];
    __syncthreads();
    const int h = hc*128 + tid;
    const float* w = ew1 + (size_t)eq*D_*H_ + h;
    float a = eb1[eq*H_ + h];
    float wpf[8];
#pragma unroll
    for (int p=0;p<8;++p) wpf[p] = w[(size_t)p*H_];
#pragma unroll 8
    for (int d=0; d<504; ++d){
        const int s = d & 7;
        const float wv = wpf[s];
        wpf[s] = w[(size_t)(d+8)*H_];
        a = fmaf(el[d], wv, a);
    }
#pragma unroll
    for (int d=504; d<512; ++d) a = fmaf(el[d], wpf[d&7], a);
    b1eff[(size_t)eq*H_ + h] = a;
}

// ---------------------------------------------------------------------------
// Kernel W: transpose + fp32->fp16 convert.  src [32][K][N] -> dst [32][N][K]
// ---------------------------------------------------------------------------
__global__ __launch_bounds__(256) void k_wconv(
    const float* __restrict__ src, _Float16* __restrict__ dst, int K, int N)
{
    __shared__ float tle[32][65];
    const int nblk = N >> 6;
    const int bpe  = (K >> 5) * nblk;
    const int eq   = blockIdx.x / bpe;
    const int rr   = blockIdx.x % bpe;
    const int k0   = (rr / nblk) << 5;
    const int n0   = (rr % nblk) << 6;
    const int tid  = threadIdx.x;
#pragma unroll
    for (int it=0; it<8; ++it){
        int idx = tid + it*256;
        int kk = idx >> 6, nn = idx & 63;
        tle[kk][nn] = src[((size_t)eq*K + k0 + kk)*N + n0 + nn];
    }
    __syncthreads();
    const int nn = tid >> 2, kc = tid & 3;
    h8 hv;
#pragma unroll
    for (int j=0;j<8;++j) hv[j] = (_Float16)tle[kc*8 + j][nn];
    *(h8*)&dst[((size_t)eq*N + n0 + nn)*K + k0 + kc*8] = hv;
}

// ---------------------------------------------------------------------------
// Kernel E (MFMA): fused sparse expert MLP, fp16 MFMA 16x16x32.
// Depth-4 B-fragment pipeline; GEMM2 B-frags + b1eff preloaded pre-barrier.
// ---------------------------------------------------------------------------
__global__ __launch_bounds__(512) void k_expert_mfma(
    const float* __restrict__ x,
    const _Float16* __restrict__ w1t,   // [32][1024][512]
    const _Float16* __restrict__ w2t,   // [32][512][1024]
    const float* __restrict__ b1eff,    // [32][1024]
    const float* __restrict__ wgt,      // [4096][8][4]
    const int* __restrict__ listtok,
    const int* __restrict__ listpr,
    const int* __restrict__ counters,
    float* __restrict__ pairout)
{
    extern __shared__ _Float16 fr[];    // XA[16384] | HA[16384]  (64 KB)
    _Float16* XA = fr;
    _Float16* HA = fr + 16384;
    __shared__ int   tokl[32];
    __shared__ int   prl[32];
    __shared__ float wscl[32];

    const int e    = blockIdx.x & 7;
    const int tile = blockIdx.x >> 3;
    const int cnt  = counters[e];
    const int base = tile * 32;
    if (base >= cnt) return;
    const int tid  = threadIdx.x;
    const int lane = tid & 63;
    const int wv   = tid >> 6;
    const int l15  = lane & 15;
    const int l4   = lane >> 4;

    if (tid < 32){
        int slot = base + tid;
        bool v = slot < cnt;
        tokl[tid] = v ? listtok[e*T_ + slot] : -1;
        prl[tid]  = v ? listpr[e*T_ + slot] : -1;
    }
    __syncthreads();

    // ---- stage X fragments (fp16, frag-order) ----
#pragma unroll
    for (int i=0;i<4;++i){
        int s = tid + i*512;               // 0..2047
        int t = s & 31, kc = s >> 5;       // kc: 8-elem chunk 0..63
        int tok = tokl[t];
        float4 a0 = make_float4(0,0,0,0), a1 = a0;
        if (tok >= 0){
            const float4* xp = (const float4*)(x + (size_t)tok*D_ + kc*8);
            a0 = xp[0]; a1 = xp[1];
        }
        h8 hv;
        hv[0]=(_Float16)a0.x; hv[1]=(_Float16)a0.y; hv[2]=(_Float16)a0.z; hv[3]=(_Float16)a0.w;
        hv[4]=(_Float16)a1.x; hv[5]=(_Float16)a1.y; hv[6]=(_Float16)a1.z; hv[7]=(_Float16)a1.w;
        int kstep = kc >> 2, msub = t >> 4, ln = (t & 15) + ((kc & 3) << 4);
        *(h8*)&XA[(((kstep<<1) + msub)*64 + ln)*8] = hv;
    }
    __syncthreads();

    f4 acc2[4][2];
#pragma unroll
    for (int nt=0;nt<4;++nt)
#pragma unroll
        for (int ms=0;ms<2;++ms) acc2[nt][ms] = (f4){0.f,0.f,0.f,0.f};

    for (int q=0; q<Q_; ++q){
        const int eq = e*4 + q;
        if (tid < 32) wscl[tid] = (tokl[tid] >= 0) ? wgt[((size_t)tokl[tid]*E_ + e)*Q_ + q] : 0.f;

        for (int hc=0; hc<2; ++hc){
            f4 acc1[4][2];
#pragma unroll
            for (int nt=0;nt<4;++nt)
#pragma unroll
                for (int ms=0;ms<2;++ms) acc1[nt][ms] = (f4){0.f,0.f,0.f,0.f};

            h8 bb[4][4];
            h8 xb[2][2];

            // ---- GEMM1: depth-4 B pipeline ----
            const _Float16* w1b = w1t + ((size_t)(eq*1024 + hc*512 + wv*64 + l15))*512 + l4*8;
#pragma unroll
            for (int p=0;p<4;++p)
#pragma unroll
                for (int nt=0;nt<4;++nt)
                    bb[p][nt] = *(const h8*)(w1b + nt*(16*512) + p*32);
#pragma unroll
            for (int ms=0;ms<2;++ms) xb[0][ms] = *(const h8*)&XA[(ms*64 + lane)*8];
#pragma unroll
            for (int ks=0; ks<16; ++ks){
                const int s = ks & 3, xc = ks & 1;
                h8 b0=bb[s][0], b1v=bb[s][1], b2v=bb[s][2], b3v=bb[s][3];
                if (ks < 12){
#pragma unroll
                    for (int nt=0;nt<4;++nt)
                        bb[s][nt] = *(const h8*)(w1b + nt*(16*512) + (ks+4)*32);
                }
                if (ks < 15){
#pragma unroll
                    for (int ms=0;ms<2;++ms)
                        xb[xc^1][ms] = *(const h8*)&XA[((((ks+1)<<1) + ms)*64 + lane)*8];
                }
#pragma unroll
                for (int ms=0;ms<2;++ms){
                    acc1[0][ms] = __builtin_amdgcn_mfma_f32_16x16x32_f16(xb[xc][ms], b0,  acc1[0][ms], 0,0,0);
                    acc1[1][ms] = __builtin_amdgcn_mfma_f32_16x16x32_f16(xb[xc][ms], b1v, acc1[1][ms], 0,0,0);
                    acc1[2][ms] = __builtin_amdgcn_mfma_f32_16x16x32_f16(xb[xc][ms], b2v, acc1[2][ms], 0,0,0);
                    acc1[3][ms] = __builtin_amdgcn_mfma_f32_16x16x32_f16(xb[xc][ms], b3v, acc1[3][ms], 0,0,0);
                }
            }

            // ---- preload GEMM2 B-frags (depth 4) + b1eff BEFORE barriers ----
            const _Float16* w2b = w2t + ((size_t)(eq*512 + wv*64 + l15))*1024 + hc*512 + l4*8;
            float bvl[4];
#pragma unroll
            for (int nt=0;nt<4;++nt)
                bvl[nt] = b1eff[eq*H_ + hc*512 + wv*64 + nt*16 + l15];
#pragma unroll
            for (int p=0;p<4;++p)
#pragma unroll
                for (int nt=0;nt<4;++nt)
                    bb[p][nt] = *(const h8*)(w2b + nt*(16*1024) + p*32);

            __syncthreads();   // prev GEMM2 done reading HA; wscl(q) visible
            // ---- epilogue: bias + gelu + w-scale -> HA fragments ----
#pragma unroll
            for (int nt=0;nt<4;++nt){
                const int hcol = wv*64 + nt*16 + l15;          // [0,512)
                const float bv = bvl[nt];
                const int ks2 = hcol >> 5;
                const int lg  = (hcol >> 3) & 3;
                const int jj  = hcol & 7;
#pragma unroll
                for (int ms=0;ms<2;++ms){
#pragma unroll
                    for (int r=0;r<4;++r){
                        const int t = ms*16 + l4*4 + r;
                        float v = acc1[nt][ms][r] + bv;
                        v = gelu_exact(v) * wscl[t];
                        HA[(((ks2<<1) + ms)*64 + ((t & 15) + (lg<<4)))*8 + jj] = (_Float16)v;
                    }
                }
            }
            __syncthreads();

            // ---- GEMM2: depth-4 B pipeline, accumulate acc2 ----
#pragma unroll
            for (int ms=0;ms<2;++ms) xb[0][ms] = *(const h8*)&HA[(ms*64 + lane)*8];
#pragma unroll
            for (int ks=0; ks<16; ++ks){
                const int s = ks & 3, xc = ks & 1;
                h8 b0=bb[s][0], b1v=bb[s][1], b2v=bb[s][2], b3v=bb[s][3];
                if (ks < 12){
#pragma unroll
                    for (int nt=0;nt<4;++nt)
                        bb[s][nt] = *(const h8*)(w2b + nt*(16*1024) + (ks+4)*32);
                }
                if (ks < 15){
#pragma unroll
                    for (int ms=0;ms<2;++ms)
                        xb[xc^1][ms] = *(const h8*)&HA[((((ks+1)<<1) + ms)*64 + lane)*8];
                }
#pragma unroll
                for (int ms=0;ms<2;++ms){
                    acc2[0][ms] = __builtin_amdgcn_mfma_f32_16x16x32_f16(xb[xc][ms], b0,  acc2[0][ms], 0,0,0);
                    acc2[1][ms] = __builtin_amdgcn_mfma_f32_16x16x32_f16(xb[xc][ms], b1v, acc2[1][ms], 0,0,0);
                    acc2[2][ms] = __builtin_amdgcn_mfma_f32_16x16x32_f16(xb[xc][ms], b2v, acc2[2][ms], 0,0,0);
                    acc2[3][ms] = __builtin_amdgcn_mfma_f32_16x16x32_f16(xb[xc][ms], b3v, acc2[3][ms], 0,0,0);
                }
            }
        }
    }

    // ---- store ----
#pragma unroll
    for (int nt=0;nt<4;++nt){
        const int col = wv*64 + nt*16 + l15;
#pragma unroll
        for (int ms=0;ms<2;++ms){
#pragma unroll
            for (int r=0;r<4;++r){
                const int t = ms*16 + l4*4 + r;
                const int pr = prl[t];
                if (pr >= 0) pairout[(size_t)pr*D_ + col] = acc2[nt][ms][r];
            }
        }
    }
}

// ---------------------------------------------------------------------------
// Kernel E (fp32 fallback, used only when ws too small for fp16 weights)
// ---------------------------------------------------------------------------
__global__ __launch_bounds__(512) void k_expert(
    const float* __restrict__ x,
    const float* __restrict__ ew1,
    const float* __restrict__ ew2,
    const float* __restrict__ b1eff,
    const float* __restrict__ wgt,
    const int* __restrict__ listtok,
    const int* __restrict__ listpr,
    const int* __restrict__ counters,
    float* __restrict__ pairout)
{
    extern __shared__ float lds[];
    float* Xs = lds;
    float* Hs = lds + D_*36;
    const int e    = blockIdx.x & 7;
    const int tile = blockIdx.x >> 3;
    const int cnt  = counters[e];
    const int base = tile * 32;
    if (base >= cnt) return;
    const int tid = threadIdx.x;
    {
        const int t = tid & 31, half = tid >> 5;
        const int slot = base + t;
        const bool v = slot < cnt;
        const int tok = v ? listtok[e*T_ + slot] : 0;
        const float* xr = x + (size_t)tok*D_ + half*32;
#pragma unroll
        for (int i=0;i<8;++i){
            float4 xv = *(const float4*)(xr + i*4);
            const int d = half*32 + i*4;
            Xs[(d+0)*36 + t] = v ? xv.x : 0.f;
            Xs[(d+1)*36 + t] = v ? xv.y : 0.f;
            Xs[(d+2)*36 + t] = v ? xv.z : 0.f;
            Xs[(d+3)*36 + t] = v ? xv.w : 0.f;
        }
    }
    __syncthreads();
    const int tgrp = tid & 7;
    const int grp  = tid >> 3;
    int mytok[4]; bool mval[4]; int mypr[4];
#pragma unroll
    for (int i=0;i<4;++i){
        int slot = base + tgrp*4 + i;
        mval[i] = slot < cnt;
        mytok[i] = mval[i] ? listtok[e*T_ + slot] : 0;
        mypr[i]  = mval[i] ? listpr[e*T_ + slot] : 0;
    }
    float c2[4][8];
#pragma unroll
    for (int i=0;i<4;++i)
#pragma unroll
        for (int j=0;j<8;++j) c2[i][j]=0.f;
    for (int q=0;q<Q_;++q){
        float wsc[4];
#pragma unroll
        for (int i=0;i<4;++i)
            wsc[i] = mval[i] ? wgt[((size_t)mytok[i]*E_ + e)*Q_ + q] : 0.f;
        for (int hc=0; hc<2; ++hc){
            float c1[4][8];
#pragma unroll
            for (int i=0;i<4;++i)
#pragma unroll
                for (int j=0;j<8;++j) c1[i][j]=0.f;
            {
                const float* w1p = ew1 + (size_t)(e*Q_+q)*D_*H_ + hc*512 + grp*8;
                float4 pa[4], pb[4], px[4];
#pragma unroll
                for (int p=0;p<4;++p){
                    const float* wr = w1p + (size_t)p*H_;
                    pa[p] = *(const float4*)wr;
                    pb[p] = *(const float4*)(wr+4);
                    px[p] = *(const float4*)&Xs[p*36 + tgrp*4];
                }
#pragma unroll 4
                for (int k=0;k<508;++k){
                    const int s = k & 3;
                    float4 wa = pa[s], wb = pb[s], xa = px[s];
                    const float* wr = w1p + (size_t)(k+4)*H_;
                    pa[s] = *(const float4*)wr;
                    pb[s] = *(const float4*)(wr+4);
                    px[s] = *(const float4*)&Xs[(k+4)*36 + tgrp*4];
                    float xs4[4] = {xa.x,xa.y,xa.z,xa.w};
                    float ww[8]  = {wa.x,wa.y,wa.z,wa.w,wb.x,wb.y,wb.z,wb.w};
#pragma unroll
                    for (int i=0;i<4;++i)
#pragma unroll
                        for (int j=0;j<8;++j)
                            c1[i][j] = fmaf(xs4[i], ww[j], c1[i][j]);
                }
#pragma unroll
                for (int k=508;k<512;++k){
                    const int s = k & 3;
                    float4 wa = pa[s], wb = pb[s], xa = px[s];
                    float xs4[4] = {xa.x,xa.y,xa.z,xa.w};
                    float ww[8]  = {wa.x,wa.y,wa.z,wa.w,wb.x,wb.y,wb.z,wb.w};
#pragma unroll
                    for (int i=0;i<4;++i)
#pragma unroll
                        for (int j=0;j<8;++j)
                            c1[i][j] = fmaf(xs4[i], ww[j], c1[i][j]);
                }
            }
            __syncthreads();
            {
                const float* b1p = b1eff + (size_t)(e*Q_+q)*H_ + hc*512 + grp*8;
#pragma unroll
                for (int j=0;j<8;++j){
                    float bj = b1p[j];
                    float h0 = gelu_exact(c1[0][j]+bj)*wsc[0];
                    float h1 = gelu_exact(c1[1][j]+bj)*wsc[1];
                    float h2 = gelu_exact(c1[2][j]+bj)*wsc[2];
                    float h3 = gelu_exact(c1[3][j]+bj)*wsc[3];
                    *(float4*)&Hs[(grp*8+j)*36 + tgrp*4] = make_float4(h0,h1,h2,h3);
                }
            }
            __syncthreads();
            {
                const float* w2p = ew2 + (size_t)(e*Q_+q)*H_*D_ + (size_t)hc*512*D_ + grp*8;
                float4 pa[4], pb[4], ph[4];
#pragma unroll
                for (int p=0;p<4;++p){
                    const float* wr = w2p + (size_t)p*D_;
                    pa[p] = *(const float4*)wr;
                    pb[p] = *(const float4*)(wr+4);
                    ph[p] = *(const float4*)&Hs[p*36 + tgrp*4];
                }
#pragma unroll 4
                for (int k2=0;k2<508;++k2){
                    const int s = k2 & 3;
                    float4 wa = pa[s], wb = pb[s], ha = ph[s];
                    const float* wr = w2p + (size_t)(k2+4)*D_;
                    pa[s] = *(const float4*)wr;
                    pb[s] = *(const float4*)(wr+4);
                    ph[s] = *(const float4*)&Hs[(k2+4)*36 + tgrp*4];
                    float hs4[4] = {ha.x,ha.y,ha.z,ha.w};
                    float ww[8]  = {wa.x,wa.y,wa.z,wa.w,wb.x,wb.y,wb.z,wb.w};
#pragma unroll
                    for (int i=0;i<4;++i)
#pragma unroll
                        for (int j=0;j<8;++j)
                            c2[i][j] = fmaf(hs4[i], ww[j], c2[i][j]);
                }
#pragma unroll
                for (int k2=508;k2<512;++k2){
                    const int s = k2 & 3;
                    float4 wa = pa[s], wb = pb[s], ha = ph[s];
                    float hs4[4] = {ha.x,ha.y,ha.z,ha.w};
                    float ww[8]  = {wa.x,wa.y,wa.z,wa.w,wb.x,wb.y,wb.z,wb.w};
#pragma unroll
                    for (int i=0;i<4;++i)
#pragma unroll
                        for (int j=0;j<8;++j)
                            c2[i][j] = fmaf(hs4[i], ww[j], c2[i][j]);
                }
            }
        }
    }
#pragma unroll
    for (int i=0;i<4;++i){
        if (mval[i]){
            float* o = pairout + (size_t)mypr[i]*D_ + grp*8;
            *(float4*)o       = make_float4(c2[i][0],c2[i][1],c2[i][2],c2[i][3]);
            *((float4*)o + 1) = make_float4(c2[i][4],c2[i][5],c2[i][6],c2[i][7]);
        }
    }
}

// ---------------------------------------------------------------------------
// Kernel C: combine pairs + eb2 bias + residual gate + LN
// ---------------------------------------------------------------------------
__global__ __launch_bounds__(128) void k_combine(
    const float* __restrict__ x,
    const float* __restrict__ pairout,
    const float* __restrict__ wgt,
    const int*  __restrict__ selexp,
    const float* __restrict__ eb2,
    const float* __restrict__ rgw, const float* __restrict__ rgb,
    const float* __restrict__ lng,
    const float* __restrict__ lnb,
    float* __restrict__ out)
{
    const int t = blockIdx.x;
    const int tid = threadIdx.x;
    const int d0 = tid*4;
    __shared__ float rbuf[6];
    const int e0 = selexp[t*2], e1 = selexp[t*2+1];
    float4 xv = *(const float4*)(x + (size_t)t*D_ + d0);
    {
        float4 rg4 = *(const float4*)(rgw + d0);
        float gp = xv.x*rg4.x + xv.y*rg4.y + xv.z*rg4.z + xv.w*rg4.w;
#pragma unroll
        for (int o=1;o<64;o<<=1) gp += __shfl_xor(gp,o,64);
        if ((tid&63)==0) rbuf[4+(tid>>6)] = gp;
    }
    __syncthreads();
    const float g = sigm(rbuf[4] + rbuf[5] + rgb[0]);

    float4 p0 = *(const float4*)(pairout + (size_t)(t*2)*D_ + d0);
    float4 p1 = *(const float4*)(pairout + (size_t)(t*2+1)*D_ + d0);
    float y[4] = {p0.x+p1.x, p0.y+p1.y, p0.z+p1.z, p0.w+p1.w};
#pragma unroll
    for (int r=0;r<2;++r){
        int e = r ? e1 : e0;
#pragma unroll
        for (int q=0;q<4;++q){
            float w = wgt[((size_t)t*E_ + e)*Q_ + q];
            float4 b = *(const float4*)(eb2 + (size_t)(e*Q_+q)*D_ + d0);
            y[0]=fmaf(w,b.x,y[0]); y[1]=fmaf(w,b.y,y[1]);
            y[2]=fmaf(w,b.z,y[2]); y[3]=fmaf(w,b.w,y[3]);
        }
    }
    float xs4[4] = {xv.x,xv.y,xv.z,xv.w};
#pragma unroll
    for (int c=0;c<4;++c) y[c] = g*y[c] + (1.f-g)*xs4[c];

    float s = y[0]+y[1]+y[2]+y[3];
#pragma unroll
    for (int o=1;o<64;o<<=1) s += __shfl_xor(s,o,64);
    if ((tid&63)==0) rbuf[tid>>6] = s;
    __syncthreads();
    float m = (rbuf[0]+rbuf[1]) * (1.0f/512.0f);
    float v = 0.f;
#pragma unroll
    for (int c=0;c<4;++c){ float dd=y[c]-m; v=fmaf(dd,dd,v); }
#pragma unroll
    for (int o=1;o<64;o<<=1) v += __shfl_xor(v,o,64);
    if ((tid&63)==0) rbuf[2+(tid>>6)] = v;
    __syncthreads();
    float var = (rbuf[2]+rbuf[3]) * (1.0f/512.0f);
    float rs = rsqrtf(var + 1e-5f);
    float4 gv = *(const float4*)(lng + d0);
    float4 bv = *(const float4*)(lnb + d0);
    float o0=(y[0]-m)*rs*gv.x+bv.x, o1=(y[1]-m)*rs*gv.y+bv.y;
    float o2=(y[2]-m)*rs*gv.z+bv.z, o3=(y[3]-m)*rs*gv.w+bv.w;
    *(float4*)(out + (size_t)t*D_ + d0) = make_float4(o0,o1,o2,o3);
}

// ---------------------------------------------------------------------------
// Kernel D: aux loss
// ---------------------------------------------------------------------------
__global__ __launch_bounds__(256) void k_aux(
    const float* __restrict__ rw, const float* __restrict__ confsum,
    float* __restrict__ aux)
{
    __shared__ float part[256*8];
    __shared__ float usage[8];
    const int tid = threadIdx.x;
    float u[8] = {0,0,0,0,0,0,0,0};
    for (int t=tid; t<T_; t+=256){
#pragma unroll
        for (int e=0;e<8;++e) u[e] += rw[(size_t)t*8+e];
    }
#pragma unroll
    for (int e=0;e<8;++e) part[tid*8+e] = u[e];
    __syncthreads();
    if (tid < 8){
        float s = 0.f;
        for (int i=0;i<256;++i) s += part[i*8+tid];
        usage[tid] = s;
    }
    __syncthreads();
    if (tid == 0){
        float S=0.f;
#pragma unroll
        for (int e=0;e<8;++e) S += usage[e];
        float mu = S * (1.0f/8.0f);
        float a = 0.f;
#pragma unroll
        for (int e=0;e<8;++e){ float dd = usage[e]-mu; a += dd*dd; }
        a = a*(1.0f/8.0f) + 0.1f*(confsum[0]*(1.0f/4096.0f));
        aux[0] = a;
    }
}

// ---------------------------------------------------------------------------
#define OFF_WGT      256
#define OFF_SELEXP   (OFF_WGT + 524288)
#define OFF_LISTTOK  (OFF_SELEXP + 32768)
#define OFF_LISTPR   (OFF_LISTTOK + 131072)
#define OFF_B1EFF    (OFF_LISTPR + 131072)
#define OFF_PAIROUT  (OFF_B1EFF + 131072)
#define OFF_W1T      (OFF_PAIROUT + 16777216)
#define OFF_W2T      (OFF_W1T + 33554432)
#define WS_NEED      ((size_t)OFF_W2T + 33554432)

extern "C" void kernel_launch(void* const* d_in, const int* in_sizes, int n_in,
                              void* d_out, int out_size, void* d_ws, size_t ws_size,
                              hipStream_t stream) {
    (void)in_sizes; (void)n_in; (void)out_size;
    const float* x      = (const float*)d_in[0];
    const float* r0_w1  = (const float*)d_in[1];
    const float* r0_b1  = (const float*)d_in[2];
    const float* r0_g   = (const float*)d_in[3];
    const float* r0_be  = (const float*)d_in[4];
    const float* r0_w2  = (const float*)d_in[5];
    const float* r0_b2  = (const float*)d_in[6];
    const float* r1_w1  = (const float*)d_in[7];
    const float* r1_b1  = (const float*)d_in[8];
    const float* r1_g   = (const float*)d_in[9];
    const float* r1_be  = (const float*)d_in[10];
    const float* r1_w2  = (const float*)d_in[11];
    const float* r1_b2  = (const float*)d_in[12];
    const float* r2_w1  = (const float*)d_in[13];
    const float* r2_b1  = (const float*)d_in[14];
    const float* r2_g   = (const float*)d_in[15];
    const float* r2_be  = (const float*)d_in[16];
    const float* r2_w2  = (const float*)d_in[17];
    const float* r2_b2  = (const float*)d_in[18];
    const float* cw1    = (const float*)d_in[19];
    const float* cb1    = (const float*)d_in[20];
    const float* cw2    = (const float*)d_in[21];
    const float* cb2    = (const float*)d_in[22];
    const float* emb    = (const float*)d_in[23];
    const float* ew1    = (const float*)d_in[24];
    const float* eb1    = (const float*)d_in[25];
    const float* ew2    = (const float*)d_in[26];
    const float* eb2    = (const float*)d_in[27];
    const float* ent    = (const float*)d_in[28];
    const float* gw     = (const float*)d_in[29];
    const float* gb     = (const float*)d_in[30];
    const float* rgw    = (const float*)d_in[31];
    const float* rgb    = (const float*)d_in[32];
    const float* lng    = (const float*)d_in[33];
    const float* lnb    = (const float*)d_in[34];

    float* outp = (float*)d_out;
    float* auxp = outp + (size_t)T_*D_;
    float* rwp  = auxp + 1;

    char* wsb = (char*)d_ws;
    int*      counters = (int*)     (wsb + 0);
    float*    confsum  = (float*)   (wsb + 32);
    float*    Wgt      = (float*)   (wsb + OFF_WGT);
    int*      SelExp   = (int*)     (wsb + OFF_SELEXP);
    int*      ListTok  = (int*)     (wsb + OFF_LISTTOK);
    int*      ListPr   = (int*)     (wsb + OFF_LISTPR);
    float*    B1eff    = (float*)   (wsb + OFF_B1EFF);
    float*    PairOut  = (float*)   (wsb + OFF_PAIROUT);
    _Float16* W1T      = (_Float16*)(wsb + OFF_W1T);
    _Float16* W2T      = (_Float16*)(wsb + OFF_W2T);

    const bool use_mfma = (ws_size >= WS_NEED);

    hipMemsetAsync(wsb, 0, 256, stream);

    if (use_mfma){
        k_wconv<<<8192, 256, 0, stream>>>(ew1, W1T, 512, 1024);
        k_wconv<<<8192, 256, 0, stream>>>(ew2, W2T, 1024, 512);
    }

    k_router<<<256, 256, 0, stream>>>(
        x, r0_w1,r0_b1,r0_g,r0_be,r0_w2,r0_b2,
           r1_w1,r1_b1,r1_g,r1_be,r1_w2,r1_b2,
           r2_w1,r2_b1,r2_g,r2_be,r2_w2,r2_b2,
        cw1,cb1,cw2,cb2, gw,gb, ent,
        rwp, Wgt, SelExp, ListTok, ListPr, counters, confsum);

    k_b1eff<<<256, 128, 0, stream>>>(emb, ew1, eb1, B1eff);

    if (use_mfma){
        hipFuncSetAttribute((const void*)k_expert_mfma,
                            hipFuncAttributeMaxDynamicSharedMemorySize, 65536);
        k_expert_mfma<<<1024, 512, 65536, stream>>>(
            x, W1T, W2T, B1eff, Wgt, ListTok, ListPr, counters, PairOut);
    } else {
        hipFuncSetAttribute((const void*)k_expert,
                            hipFuncAttributeMaxDynamicSharedMemorySize, 2*D_*36*4);
        k_expert<<<1024, 512, 2*D_*36*4, stream>>>(
            x, ew1, ew2, B1eff, Wgt, ListTok, ListPr, counters, PairOut);
    }

    k_combine<<<T_, 128, 0, stream>>>(
        x, PairOut, Wgt, SelExp, eb2, rgw, rgb, lng, lnb, outp);

    k_aux<<<1, 256, 0, stream>>>(rwp, confsum, auxp);
}

// Round 6
// 893.520 us; speedup vs baseline: 1.2080x; 1.2080x over previous
//
#include <hip/hip_runtime.h>
#include <math.h>

#define T_ 4096
#define D_ 512
#define H_ 1024
#define E_ 8
#define Q_ 4

typedef _Float16 h8 __attribute__((ext_vector_type(8)));
typedef float f4 __attribute__((ext_vector_type(4)));

__device__ __forceinline__ float gelu_exact(float v){
    return 0.5f * v * (1.0f + erff(v * 0.70710678118654752440f));
}
__device__ __forceinline__ float sigm(float v){
    return 1.0f / (1.0f + expf(-v));
}

// ---------------------------------------------------------------------------
// Router level (8 tokens/block): hidden(256)=gelu(x@w1+b1) -> LN -> logits
// ---------------------------------------------------------------------------
template<int OUTL>
__device__ void router_level(
    const float* __restrict__ xg,
    const float* __restrict__ w1, const float* __restrict__ b1,
    const float* __restrict__ g,  const float* __restrict__ be,
    const float* __restrict__ w2, const float* __restrict__ b2,
    float* __restrict__ Hl, float* __restrict__ logit,
    float* __restrict__ mrs, float* __restrict__ red, int tid)
{
    float acc[8];
#pragma unroll
    for (int t=0;t<8;++t) acc[t]=0.f;
    const float bb = b1[tid];
    {
        float wpf[8];
#pragma unroll
        for (int p=0;p<8;++p) wpf[p] = w1[p*256 + tid];
#pragma unroll 8
        for (int d=0; d<504; ++d){
            const int s = d & 7;
            const float w = wpf[s];
            wpf[s] = w1[(d+8)*256 + tid];
#pragma unroll
            for (int t=0;t<8;++t) acc[t] = fmaf(xg[t*D_ + d], w, acc[t]);
        }
#pragma unroll
        for (int d=504; d<512; ++d){
            const float w = wpf[d & 7];
#pragma unroll
            for (int t=0;t<8;++t) acc[t] = fmaf(xg[t*D_ + d], w, acc[t]);
        }
    }
#pragma unroll
    for (int t=0;t<8;++t) Hl[t*264 + tid] = gelu_exact(acc[t] + bb);
    __syncthreads();
    {
        int wid = tid >> 6, lane = tid & 63;
#pragma unroll
        for (int tt=0; tt<2; ++tt){
            int t = wid*2 + tt;
            float s = Hl[t*264+lane] + Hl[t*264+lane+64] + Hl[t*264+lane+128] + Hl[t*264+lane+192];
#pragma unroll
            for (int o=1;o<64;o<<=1) s += __shfl_xor(s, o, 64);
            float m = s * (1.0f/256.0f);
            float v = 0.f;
#pragma unroll
            for (int r=0;r<4;++r){ float dd = Hl[t*264+lane+64*r] - m; v = fmaf(dd,dd,v); }
#pragma unroll
            for (int o=1;o<64;o<<=1) v += __shfl_xor(v, o, 64);
            if (lane==0){ mrs[t*2+0] = m; mrs[t*2+1] = rsqrtf(v*(1.0f/256.0f) + 1e-5f); }
        }
    }
    __syncthreads();
#pragma unroll
    for (int t=0;t<8;++t){
        float hv = Hl[t*264+tid];
        Hl[t*264+tid] = (hv - mrs[t*2]) * mrs[t*2+1] * g[tid] + be[tid];
    }
    __syncthreads();
    {
        const int t = tid & 7, kk = (tid>>3) & 7, quarter = tid >> 6;
        const int col = kk & (OUTL-1);
        const float* w2q = w2 + (size_t)quarter*64*OUTL + col;
        const float* hq  = Hl + t*264 + quarter*64;
        float a = 0.f;
#pragma unroll 8
        for (int j=0;j<64;++j) a = fmaf(hq[j], w2q[j*OUTL], a);
        red[tid] = a;
    }
    __syncthreads();
    if (tid < 64){
        const int t = tid & 7, kk = tid >> 3;
        float s = red[tid] + red[tid+64] + red[tid+128] + red[tid+192] + b2[kk & (OUTL-1)];
        if (OUTL == 8) logit[t*8+kk] = s;
        else           logit[t*8+kk] += s;
    }
    __syncthreads();
}

// ---------------------------------------------------------------------------
// Kernel A: router + confidence + top2 + gating. 8 tokens/block, 512 blocks.
// ---------------------------------------------------------------------------
__global__ __launch_bounds__(256) void k_router(
    const float* __restrict__ x,
    const float* __restrict__ r0_w1, const float* __restrict__ r0_b1,
    const float* __restrict__ r0_g,  const float* __restrict__ r0_be,
    const float* __restrict__ r0_w2, const float* __restrict__ r0_b2,
    const float* __restrict__ r1_w1, const float* __restrict__ r1_b1,
    const float* __restrict__ r1_g,  const float* __restrict__ r1_be,
    const float* __restrict__ r1_w2, const float* __restrict__ r1_b2,
    const float* __restrict__ r2_w1, const float* __restrict__ r2_b1,
    const float* __restrict__ r2_g,  const float* __restrict__ r2_be,
    const float* __restrict__ r2_w2, const float* __restrict__ r2_b2,
    const float* __restrict__ cw1, const float* __restrict__ cb1,
    const float* __restrict__ cw2, const float* __restrict__ cb2,
    const float* __restrict__ gw, const float* __restrict__ gb,
    const float* __restrict__ ent,
    float* __restrict__ out_rw,
    float* __restrict__ wgt,
    int* __restrict__ selexp, int* __restrict__ listtok, int* __restrict__ listpr,
    int* __restrict__ counters, float* __restrict__ confsum)
{
    __shared__ float Xl[8*520];
    __shared__ float Hl[8*264];
    __shared__ float red[2048];
    __shared__ float h1c[512];
    __shared__ float logit[64];
    __shared__ float rwl[64];
    __shared__ float spl[256];
    __shared__ float mrs[16];

    const int tid = threadIdx.x;
    const int tb  = blockIdx.x * 8;
    const float* xg = x + (size_t)tb * D_;
    {
        const float4* xv = (const float4*)xg;
#pragma unroll
        for (int r=0;r<4;++r){
            int i = r*256 + tid;
            int t = i >> 7, c = i & 127;
            float4 v = xv[i];
            Xl[t*520 + c*4 + 0] = v.x;
            Xl[t*520 + c*4 + 1] = v.y;
            Xl[t*520 + c*4 + 2] = v.z;
            Xl[t*520 + c*4 + 3] = v.w;
        }
    }
    __syncthreads();
    {
        int j = tid & 63, seg = tid >> 6;
        float a[8];
#pragma unroll
        for (int t=0;t<8;++t) a[t]=0.f;
        for (int d = seg*128; d < seg*128+128; ++d){
            float w = cw1[d*64 + j];
#pragma unroll
            for (int t=0;t<8;++t) a[t] = fmaf(Xl[t*520+d], w, a[t]);
        }
#pragma unroll
        for (int t=0;t<8;++t) red[(seg*64+j)*8 + t] = a[t];
    }
    __syncthreads();
    if (tid < 64){
        int j = tid;
#pragma unroll
        for (int t=0;t<8;++t){
            float s = red[j*8+t] + red[(64+j)*8+t] + red[(128+j)*8+t] + red[(192+j)*8+t];
            h1c[t*64+j] = tanhf(s + cb1[j]);
        }
    }
    __syncthreads();
    if (tid < 8){
        float a = cb2[0];
        for (int j=0;j<64;++j) a = fmaf(h1c[tid*64+j], cw2[j], a);
        float c = sigm(a);
        atomicAdd(confsum, fabsf(c - 0.7f));
    }
    __syncthreads();

    router_level<8>(xg, r0_w1,r0_b1,r0_g,r0_be,r0_w2,r0_b2, Hl, logit, mrs, red, tid);
    router_level<4>(xg, r1_w1,r1_b1,r1_g,r1_be,r1_w2,r1_b2, Hl, logit, mrs, red, tid);
    router_level<2>(xg, r2_w1,r2_b1,r2_g,r2_be,r2_w2,r2_b2, Hl, logit, mrs, red, tid);

    if (tid < 8){
        int t = tid;
        float l[8], p[8];
        float mx = -1e30f;
#pragma unroll
        for (int e=0;e<8;++e){ l[e]=logit[t*8+e]; mx = fmaxf(mx, l[e]); }
        float s=0.f;
#pragma unroll
        for (int e=0;e<8;++e){ p[e]=expf(l[e]-mx); s+=p[e]; }
        float inv = 1.f/s;
#pragma unroll
        for (int e=0;e<8;++e) p[e]*=inv;
        int i1=0; float v1=p[0];
#pragma unroll
        for (int e=1;e<8;++e) if (p[e] > v1){ v1=p[e]; i1=e; }
        int i2=-1; float v2=-1e30f;
#pragma unroll
        for (int e=0;e<8;++e) if (e!=i1 && p[e] > v2){ v2=p[e]; i2=e; }
        float denom = 1.f/(v1 + v2 + 1e-10f);
#pragma unroll
        for (int e=0;e<8;++e){
            float rv = (e==i1 || e==i2) ? p[e]*denom : 0.f;
            out_rw[(size_t)(tb+t)*8 + e] = rv;
            rwl[t*8+e] = rv;
        }
        selexp[(tb+t)*2+0] = i1;
        selexp[(tb+t)*2+1] = i2;
        int pos1 = atomicAdd(&counters[i1], 1);
        listtok[i1*T_+pos1] = tb+t; listpr[i1*T_+pos1] = (tb+t)*2;
        int pos2 = atomicAdd(&counters[i2], 1);
        listtok[i2*T_+pos2] = tb+t; listpr[i2*T_+pos2] = (tb+t)*2+1;
    }
    __syncthreads();
    {
        int t = tid >> 5, eqq = tid & 31, e = eqq >> 2, q = eqq & 3;
        const float* gwp = gw + e*2048 + q;
        float a = gb[e*4+q];
        float gpf[8];
#pragma unroll
        for (int p=0;p<8;++p) gpf[p] = gwp[p*4];
#pragma unroll 8
        for (int d=0; d<504; ++d){
            const int s = d & 7;
            const float w = gpf[s];
            gpf[s] = gwp[(d+8)*4];
            a = fmaf(Xl[t*520+d], w, a);
        }
#pragma unroll
        for (int d=504; d<512; ++d)
            a = fmaf(Xl[t*520+d], gpf[d&7], a);
        spl[(t*8+e)*4+q] = a;
    }
    __syncthreads();
    if (tid < 64){
        int t = tid >> 3, e = tid & 7;
        float spv[4]; float mx=-1e30f;
#pragma unroll
        for (int q=0;q<4;++q){ spv[q]=spl[(t*8+e)*4+q]; mx=fmaxf(mx,spv[q]); }
        float ss=0.f;
#pragma unroll
        for (int q=0;q<4;++q){ spv[q]=expf(spv[q]-mx); ss+=spv[q]; }
        float inv=1.f/ss;
#pragma unroll
        for (int q=0;q<4;++q) spv[q]*=inv;
        float epv[4]; float mx2=-1e30f;
#pragma unroll
        for (int r=0;r<4;++r){
            float a = spv[0]*ent[e*16+r] + spv[1]*ent[e*16+4+r]
                    + spv[2]*ent[e*16+8+r] + spv[3]*ent[e*16+12+r];
            epv[r]=a; mx2=fmaxf(mx2,a);
        }
        float s2=0.f;
#pragma unroll
        for (int r=0;r<4;++r){ epv[r]=expf(epv[r]-mx2); s2+=epv[r]; }
        float inv2=1.f/s2;
        float rwv = rwl[t*8+e];
#pragma unroll
        for (int r=0;r<4;++r)
            wgt[((size_t)(tb+t)*E_ + e)*Q_ + r] = rwv * epv[r] * inv2;
    }
}

// ---------------------------------------------------------------------------
// Kernel B: b1_eff[e,q,h] = eb1[e,q,h] + sum_d emb[e,q,d]*ew1[e,q,d,h]
// ---------------------------------------------------------------------------
__global__ __launch_bounds__(128) void k_b1eff(
    const float* __restrict__ emb, const float* __restrict__ ew1,
    const float* __restrict__ eb1, float* __restrict__ b1eff)
{
    const int eq = blockIdx.x >> 3;
    const int hc = blockIdx.x & 7;
    __shared__ float el[512];
    const int tid = threadIdx.x;
    for (int i=tid;i<512;i+=128) el[i] = emb[eq*512+i];
    __syncthreads();
    const int h = hc*128 + tid;
    const float* w = ew1 + (size_t)eq*D_*H_ + h;
    float a = eb1[eq*H_ + h];
    float wpf[8];
#pragma unroll
    for (int p=0;p<8;++p) wpf[p] = w[(size_t)p*H_];
#pragma unroll 8
    for (int d=0; d<504; ++d){
        const int s = d & 7;
        const float wv = wpf[s];
        wpf[s] = w[(size_t)(d+8)*H_];
        a = fmaf(el[d], wv, a);
    }
#pragma unroll
    for (int d=504; d<512; ++d) a = fmaf(el[d], wpf[d&7], a);
    b1eff[(size_t)eq*H_ + h] = a;
}

// ---------------------------------------------------------------------------
// Kernel W2: pack fp32 weights into per-ks fragment chunks, fp16.
// src [32][K][N].  dst chunk layout: [eq][c][cg 32][l4 4][l15 16][j 8] fp16,
// where c = nb*(K/32) + kc;  k = kc*32 + l4*8 + j;  n = nb*512 + cg*16 + l15.
// Each chunk = 16384 fp16 = 32 KB = one GEMM K-step for 512 cols.
// ---------------------------------------------------------------------------
__global__ __launch_bounds__(256) void k_wconv2(
    const float* __restrict__ src, _Float16* __restrict__ dst, int K, int N)
{
    const int kchunks = K >> 5;
    const int eq = blockIdx.x >> 5;
    const int c  = blockIdx.x & 31;
    const int nb = c / kchunks;
    const int kc = c - nb*kchunks;
    const int tid = threadIdx.x;
    _Float16* chunk = dst + ((size_t)eq*32 + c)*16384;
#pragma unroll
    for (int it=0; it<8; ++it){
        const int ridx = it*256 + tid;        // 0..2047
        const int cg  = ridx >> 6;
        const int l4  = (ridx >> 4) & 3;
        const int l15 = ridx & 15;
        const int k0  = kc*32 + l4*8;
        const int n   = nb*512 + cg*16 + l15;
        const float* s = src + ((size_t)eq*K + k0)*N + n;
        h8 hv;
#pragma unroll
        for (int j=0;j<8;++j) hv[j] = (_Float16)s[(size_t)j*N];
        *(h8*)&chunk[(size_t)ridx*8] = hv;
    }
}

// ---------------------------------------------------------------------------
// Kernel E (MFMA): fused sparse expert MLP, fp16 MFMA 16x16x32.
// B staged via LDS double-buffer (m97 pattern): reg-load chunk ks+1 early,
// ds_write after MFMAs of ks, barrier per K-step. Weight chunks pre-packed so
// staging loads are lane-contiguous 1KB bursts and ds_read_b128 of fragments
// is conflict-free.  LDS: XA 32K | HA 32K | BB 2x32K = 128 KB (1 block/CU).
// ---------------------------------------------------------------------------
__global__ __launch_bounds__(512) void k_expert_mfma(
    const float* __restrict__ x,
    const _Float16* __restrict__ w1t,   // [32][32 chunks][16384]
    const _Float16* __restrict__ w2t,   // [32][32 chunks][16384]
    const float* __restrict__ b1eff,    // [32][1024]
    const float* __restrict__ wgt,      // [4096][8][4]
    const int* __restrict__ listtok,
    const int* __restrict__ listpr,
    const int* __restrict__ counters,
    float* __restrict__ pairout)
{
    extern __shared__ char ldsraw[];
    _Float16* XA = (_Float16*)ldsraw;              // [16][2][64][8]
    _Float16* HA = (_Float16*)(ldsraw + 32768);    // [16][2][64][8]
    _Float16* BB = (_Float16*)(ldsraw + 65536);    // [2][16384]
    __shared__ int   tokl[32];
    __shared__ int   prl[32];
    __shared__ float wscl[32];

    const int e    = blockIdx.x & 7;       // expert == XCD (bid%8)
    const int tile = blockIdx.x >> 3;
    const int cnt  = counters[e];
    const int base = tile * 32;
    if (base >= cnt) return;
    const int tid  = threadIdx.x;
    const int lane = tid & 63;
    const int wv   = tid >> 6;
    const int l15  = lane & 15;
    const int l4   = lane >> 4;

    if (tid < 32){
        int slot = base + tid;
        bool v = slot < cnt;
        tokl[tid] = v ? listtok[e*T_ + slot] : -1;
        prl[tid]  = v ? listpr[e*T_ + slot] : -1;
    }
    __syncthreads();

    // ---- stage X fragments (fp16, frag-order) ----
#pragma unroll
    for (int i=0;i<4;++i){
        int s = tid + i*512;               // 0..2047
        int t = s & 31, kc = s >> 5;       // kc: 8-elem chunk 0..63
        int tok = tokl[t];
        float4 a0 = make_float4(0,0,0,0), a1 = a0;
        if (tok >= 0){
            const float4* xp = (const float4*)(x + (size_t)tok*D_ + kc*8);
            a0 = xp[0]; a1 = xp[1];
        }
        h8 hv;
        hv[0]=(_Float16)a0.x; hv[1]=(_Float16)a0.y; hv[2]=(_Float16)a0.z; hv[3]=(_Float16)a0.w;
        hv[4]=(_Float16)a1.x; hv[5]=(_Float16)a1.y; hv[6]=(_Float16)a1.z; hv[7]=(_Float16)a1.w;
        int kstep = kc >> 2, msub = t >> 4, ln = (t & 15) + ((kc & 3) << 4);
        *(h8*)&XA[(((kstep<<1) + msub)*64 + ln)*8] = hv;
    }
    __syncthreads();

    f4 acc2[4][2];
#pragma unroll
    for (int nt=0;nt<4;++nt)
#pragma unroll
        for (int ms=0;ms<2;++ms) acc2[nt][ms] = (f4){0.f,0.f,0.f,0.f};

    for (int q=0; q<Q_; ++q){
        const int eq = e*4 + q;
        if (tid < 32) wscl[tid] = (tokl[tid] >= 0) ? wgt[((size_t)tokl[tid]*E_ + e)*Q_ + q] : 0.f;

        for (int hc=0; hc<2; ++hc){
            const _Float16* cb1p = w1t + ((size_t)(eq*32 + hc*16))*16384;
            const _Float16* cb2p = w2t + ((size_t)(eq*32 + hc*16))*16384;

            // ================= GEMM1 =================
            f4 acc1[4][2];
#pragma unroll
            for (int nt=0;nt<4;++nt)
#pragma unroll
                for (int ms=0;ms<2;++ms) acc1[nt][ms] = (f4){0.f,0.f,0.f,0.f};

            {   // prologue: stage chunk 0 into buf0
                h8 s0 = *(const h8*)(cb1p + (size_t)tid*8);
                h8 s1 = *(const h8*)(cb1p + (size_t)(512  + tid)*8);
                h8 s2 = *(const h8*)(cb1p + (size_t)(1024 + tid)*8);
                h8 s3 = *(const h8*)(cb1p + (size_t)(1536 + tid)*8);
                *(h8*)&BB[(size_t)tid*8]          = s0;
                *(h8*)&BB[(size_t)(512  + tid)*8] = s1;
                *(h8*)&BB[(size_t)(1024 + tid)*8] = s2;
                *(h8*)&BB[(size_t)(1536 + tid)*8] = s3;
            }
            __syncthreads();

#pragma unroll 1
            for (int ks=0; ks<16; ++ks){
                const int cur = (ks & 1) << 14;
                h8 s0, s1, s2, s3;
                if (ks < 15){
                    const _Float16* cp = cb1p + (size_t)(ks+1)*16384;
                    s0 = *(const h8*)(cp + (size_t)tid*8);
                    s1 = *(const h8*)(cp + (size_t)(512  + tid)*8);
                    s2 = *(const h8*)(cp + (size_t)(1024 + tid)*8);
                    s3 = *(const h8*)(cp + (size_t)(1536 + tid)*8);
                }
                const h8 xb0 = *(const h8*)&XA[((ks*2+0)*64 + lane)*8];
                const h8 xb1 = *(const h8*)&XA[((ks*2+1)*64 + lane)*8];
                const h8 bf0 = *(const h8*)&BB[cur + ((wv*4+0)*64 + lane)*8];
                const h8 bf1 = *(const h8*)&BB[cur + ((wv*4+1)*64 + lane)*8];
                const h8 bf2 = *(const h8*)&BB[cur + ((wv*4+2)*64 + lane)*8];
                const h8 bf3 = *(const h8*)&BB[cur + ((wv*4+3)*64 + lane)*8];
                acc1[0][0] = __builtin_amdgcn_mfma_f32_16x16x32_f16(xb0, bf0, acc1[0][0],0,0,0);
                acc1[0][1] = __builtin_amdgcn_mfma_f32_16x16x32_f16(xb1, bf0, acc1[0][1],0,0,0);
                acc1[1][0] = __builtin_amdgcn_mfma_f32_16x16x32_f16(xb0, bf1, acc1[1][0],0,0,0);
                acc1[1][1] = __builtin_amdgcn_mfma_f32_16x16x32_f16(xb1, bf1, acc1[1][1],0,0,0);
                acc1[2][0] = __builtin_amdgcn_mfma_f32_16x16x32_f16(xb0, bf2, acc1[2][0],0,0,0);
                acc1[2][1] = __builtin_amdgcn_mfma_f32_16x16x32_f16(xb1, bf2, acc1[2][1],0,0,0);
                acc1[3][0] = __builtin_amdgcn_mfma_f32_16x16x32_f16(xb0, bf3, acc1[3][0],0,0,0);
                acc1[3][1] = __builtin_amdgcn_mfma_f32_16x16x32_f16(xb1, bf3, acc1[3][1],0,0,0);
                if (ks < 15){
                    const int nxt = ((ks+1) & 1) << 14;
                    *(h8*)&BB[nxt + (size_t)tid*8]          = s0;
                    *(h8*)&BB[nxt + (size_t)(512  + tid)*8] = s1;
                    *(h8*)&BB[nxt + (size_t)(1024 + tid)*8] = s2;
                    *(h8*)&BB[nxt + (size_t)(1536 + tid)*8] = s3;
                }
                __syncthreads();
            }

            // ---- epilogue: bias + gelu + w-scale -> HA fragments ----
            float bvl[4];
#pragma unroll
            for (int nt=0;nt<4;++nt)
                bvl[nt] = b1eff[eq*H_ + hc*512 + wv*64 + nt*16 + l15];
#pragma unroll
            for (int nt=0;nt<4;++nt){
                const int hcol = wv*64 + nt*16 + l15;          // [0,512)
                const float bv = bvl[nt];
                const int ks2 = hcol >> 5;
                const int lg  = (hcol >> 3) & 3;
                const int jj  = hcol & 7;
#pragma unroll
                for (int ms=0;ms<2;++ms){
#pragma unroll
                    for (int r=0;r<4;++r){
                        const int t = ms*16 + l4*4 + r;
                        float v = acc1[nt][ms][r] + bv;
                        v = gelu_exact(v) * wscl[t];
                        HA[(((ks2<<1) + ms)*64 + ((t & 15) + (lg<<4)))*8 + jj] = (_Float16)v;
                    }
                }
            }
            __syncthreads();

            // ================= GEMM2 =================
            {   // prologue: stage chunk 0 into buf0
                h8 s0 = *(const h8*)(cb2p + (size_t)tid*8);
                h8 s1 = *(const h8*)(cb2p + (size_t)(512  + tid)*8);
                h8 s2 = *(const h8*)(cb2p + (size_t)(1024 + tid)*8);
                h8 s3 = *(const h8*)(cb2p + (size_t)(1536 + tid)*8);
                *(h8*)&BB[(size_t)tid*8]          = s0;
                *(h8*)&BB[(size_t)(512  + tid)*8] = s1;
                *(h8*)&BB[(size_t)(1024 + tid)*8] = s2;
                *(h8*)&BB[(size_t)(1536 + tid)*8] = s3;
            }
            __syncthreads();

#pragma unroll 1
            for (int ks=0; ks<16; ++ks){
                const int cur = (ks & 1) << 14;
                h8 s0, s1, s2, s3;
                if (ks < 15){
                    const _Float16* cp = cb2p + (size_t)(ks+1)*16384;
                    s0 = *(const h8*)(cp + (size_t)tid*8);
                    s1 = *(const h8*)(cp + (size_t)(512  + tid)*8);
                    s2 = *(const h8*)(cp + (size_t)(1024 + tid)*8);
                    s3 = *(const h8*)(cp + (size_t)(1536 + tid)*8);
                }
                const h8 hb0 = *(const h8*)&HA[((ks*2+0)*64 + lane)*8];
                const h8 hb1 = *(const h8*)&HA[((ks*2+1)*64 + lane)*8];
                const h8 bf0 = *(const h8*)&BB[cur + ((wv*4+0)*64 + lane)*8];
                const h8 bf1 = *(const h8*)&BB[cur + ((wv*4+1)*64 + lane)*8];
                const h8 bf2 = *(const h8*)&BB[cur + ((wv*4+2)*64 + lane)*8];
                const h8 bf3 = *(const h8*)&BB[cur + ((wv*4+3)*64 + lane)*8];
                acc2[0][0] = __builtin_amdgcn_mfma_f32_16x16x32_f16(hb0, bf0, acc2[0][0],0,0,0);
                acc2[0][1] = __builtin_amdgcn_mfma_f32_16x16x32_f16(hb1, bf0, acc2[0][1],0,0,0);
                acc2[1][0] = __builtin_amdgcn_mfma_f32_16x16x32_f16(hb0, bf1, acc2[1][0],0,0,0);
                acc2[1][1] = __builtin_amdgcn_mfma_f32_16x16x32_f16(hb1, bf1, acc2[1][1],0,0,0);
                acc2[2][0] = __builtin_amdgcn_mfma_f32_16x16x32_f16(hb0, bf2, acc2[2][0],0,0,0);
                acc2[2][1] = __builtin_amdgcn_mfma_f32_16x16x32_f16(hb1, bf2, acc2[2][1],0,0,0);
                acc2[3][0] = __builtin_amdgcn_mfma_f32_16x16x32_f16(hb0, bf3, acc2[3][0],0,0,0);
                acc2[3][1] = __builtin_amdgcn_mfma_f32_16x16x32_f16(hb1, bf3, acc2[3][1],0,0,0);
                if (ks < 15){
                    const int nxt = ((ks+1) & 1) << 14;
                    *(h8*)&BB[nxt + (size_t)tid*8]          = s0;
                    *(h8*)&BB[nxt + (size_t)(512  + tid)*8] = s1;
                    *(h8*)&BB[nxt + (size_t)(1024 + tid)*8] = s2;
                    *(h8*)&BB[nxt + (size_t)(1536 + tid)*8] = s3;
                }
                __syncthreads();
            }
        }
    }

    // ---- store ----
#pragma unroll
    for (int nt=0;nt<4;++nt){
        const int col = wv*64 + nt*16 + l15;
#pragma unroll
        for (int ms=0;ms<2;++ms){
#pragma unroll
            for (int r=0;r<4;++r){
                const int t = ms*16 + l4*4 + r;
                const int pr = prl[t];
                if (pr >= 0) pairout[(size_t)pr*D_ + col] = acc2[nt][ms][r];
            }
        }
    }
}

// ---------------------------------------------------------------------------
// Kernel C: combine pairs + eb2 bias + residual gate + LN
// ---------------------------------------------------------------------------
__global__ __launch_bounds__(128) void k_combine(
    const float* __restrict__ x,
    const float* __restrict__ pairout,
    const float* __restrict__ wgt,
    const int*  __restrict__ selexp,
    const float* __restrict__ eb2,
    const float* __restrict__ rgw, const float* __restrict__ rgb,
    const float* __restrict__ lng,
    const float* __restrict__ lnb,
    float* __restrict__ out)
{
    const int t = blockIdx.x;
    const int tid = threadIdx.x;
    const int d0 = tid*4;
    __shared__ float rbuf[6];
    const int e0 = selexp[t*2], e1 = selexp[t*2+1];
    float4 xv = *(const float4*)(x + (size_t)t*D_ + d0);
    {
        float4 rg4 = *(const float4*)(rgw + d0);
        float gp = xv.x*rg4.x + xv.y*rg4.y + xv.z*rg4.z + xv.w*rg4.w;
#pragma unroll
        for (int o=1;o<64;o<<=1) gp += __shfl_xor(gp,o,64);
        if ((tid&63)==0) rbuf[4+(tid>>6)] = gp;
    }
    __syncthreads();
    const float g = sigm(rbuf[4] + rbuf[5] + rgb[0]);

    float4 p0 = *(const float4*)(pairout + (size_t)(t*2)*D_ + d0);
    float4 p1 = *(const float4*)(pairout + (size_t)(t*2+1)*D_ + d0);
    float y[4] = {p0.x+p1.x, p0.y+p1.y, p0.z+p1.z, p0.w+p1.w};
#pragma unroll
    for (int r=0;r<2;++r){
        int e = r ? e1 : e0;
#pragma unroll
        for (int q=0;q<4;++q){
            float w = wgt[((size_t)t*E_ + e)*Q_ + q];
            float4 b = *(const float4*)(eb2 + (size_t)(e*Q_+q)*D_ + d0);
            y[0]=fmaf(w,b.x,y[0]); y[1]=fmaf(w,b.y,y[1]);
            y[2]=fmaf(w,b.z,y[2]); y[3]=fmaf(w,b.w,y[3]);
        }
    }
    float xs4[4] = {xv.x,xv.y,xv.z,xv.w};
#pragma unroll
    for (int c=0;c<4;++c) y[c] = g*y[c] + (1.f-g)*xs4[c];

    float s = y[0]+y[1]+y[2]+y[3];
#pragma unroll
    for (int o=1;o<64;o<<=1) s += __shfl_xor(s,o,64);
    if ((tid&63)==0) rbuf[tid>>6] = s;
    __syncthreads();
    float m = (rbuf[0]+rbuf[1]) * (1.0f/512.0f);
    float v = 0.f;
#pragma unroll
    for (int c=0;c<4;++c){ float dd=y[c]-m; v=fmaf(dd,dd,v); }
#pragma unroll
    for (int o=1;o<64;o<<=1) v += __shfl_xor(v,o,64);
    if ((tid&63)==0) rbuf[2+(tid>>6)] = v;
    __syncthreads();
    float var = (rbuf[2]+rbuf[3]) * (1.0f/512.0f);
    float rs = rsqrtf(var + 1e-5f);
    float4 gv = *(const float4*)(lng + d0);
    float4 bv = *(const float4*)(lnb + d0);
    float o0=(y[0]-m)*rs*gv.x+bv.x, o1=(y[1]-m)*rs*gv.y+bv.y;
    float o2=(y[2]-m)*rs*gv.z+bv.z, o3=(y[3]-m)*rs*gv.w+bv.w;
    *(float4*)(out + (size_t)t*D_ + d0) = make_float4(o0,o1,o2,o3);
}

// ---------------------------------------------------------------------------
// Kernel D: aux loss
// ---------------------------------------------------------------------------
__global__ __launch_bounds__(256) void k_aux(
    const float* __restrict__ rw, const float* __restrict__ confsum,
    float* __restrict__ aux)
{
    __shared__ float part[256*8];
    __shared__ float usage[8];
    const int tid = threadIdx.x;
    float u[8] = {0,0,0,0,0,0,0,0};
    for (int t=tid; t<T_; t+=256){
#pragma unroll
        for (int e=0;e<8;++e) u[e] += rw[(size_t)t*8+e];
    }
#pragma unroll
    for (int e=0;e<8;++e) part[tid*8+e] = u[e];
    __syncthreads();
    if (tid < 8){
        float s = 0.f;
        for (int i=0;i<256;++i) s += part[i*8+tid];
        usage[tid] = s;
    }
    __syncthreads();
    if (tid == 0){
        float S=0.f;
#pragma unroll
        for (int e=0;e<8;++e) S += usage[e];
        float mu = S * (1.0f/8.0f);
        float a = 0.f;
#pragma unroll
        for (int e=0;e<8;++e){ float dd = usage[e]-mu; a += dd*dd; }
        a = a*(1.0f/8.0f) + 0.1f*(confsum[0]*(1.0f/4096.0f));
        aux[0] = a;
    }
}

// ---------------------------------------------------------------------------
#define OFF_WGT      256
#define OFF_SELEXP   (OFF_WGT + 524288)
#define OFF_LISTTOK  (OFF_SELEXP + 32768)
#define OFF_LISTPR   (OFF_LISTTOK + 131072)
#define OFF_B1EFF    (OFF_LISTPR + 131072)
#define OFF_PAIROUT  (OFF_B1EFF + 131072)
#define OFF_W1T      (OFF_PAIROUT + 16777216)
#define OFF_W2T      (OFF_W1T + 33554432)

extern "C" void kernel_launch(void* const* d_in, const int* in_sizes, int n_in,
                              void* d_out, int out_size, void* d_ws, size_t ws_size,
                              hipStream_t stream) {
    (void)in_sizes; (void)n_in; (void)out_size; (void)ws_size;
    const float* x      = (const float*)d_in[0];
    const float* r0_w1  = (const float*)d_in[1];
    const float* r0_b1  = (const float*)d_in[2];
    const float* r0_g   = (const float*)d_in[3];
    const float* r0_be  = (const float*)d_in[4];
    const float* r0_w2  = (const float*)d_in[5];
    const float* r0_b2  = (const float*)d_in[6];
    const float* r1_w1  = (const float*)d_in[7];
    const float* r1_b1  = (const float*)d_in[8];
    const float* r1_g   = (const float*)d_in[9];
    const float* r1_be  = (const float*)d_in[10];
    const float* r1_w2  = (const float*)d_in[11];
    const float* r1_b2  = (const float*)d_in[12];
    const float* r2_w1  = (const float*)d_in[13];
    const float* r2_b1  = (const float*)d_in[14];
    const float* r2_g   = (const float*)d_in[15];
    const float* r2_be  = (const float*)d_in[16];
    const float* r2_w2  = (const float*)d_in[17];
    const float* r2_b2  = (const float*)d_in[18];
    const float* cw1    = (const float*)d_in[19];
    const float* cb1    = (const float*)d_in[20];
    const float* cw2    = (const float*)d_in[21];
    const float* cb2    = (const float*)d_in[22];
    const float* emb    = (const float*)d_in[23];
    const float* ew1    = (const float*)d_in[24];
    const float* eb1    = (const float*)d_in[25];
    const float* ew2    = (const float*)d_in[26];
    const float* eb2    = (const float*)d_in[27];
    const float* ent    = (const float*)d_in[28];
    const float* gw     = (const float*)d_in[29];
    const float* gb     = (const float*)d_in[30];
    const float* rgw    = (const float*)d_in[31];
    const float* rgb    = (const float*)d_in[32];
    const float* lng    = (const float*)d_in[33];
    const float* lnb    = (const float*)d_in[34];

    float* outp = (float*)d_out;
    float* auxp = outp + (size_t)T_*D_;
    float* rwp  = auxp + 1;

    char* wsb = (char*)d_ws;
    int*      counters = (int*)     (wsb + 0);
    float*    confsum  = (float*)   (wsb + 32);
    float*    Wgt      = (float*)   (wsb + OFF_WGT);
    int*      SelExp   = (int*)     (wsb + OFF_SELEXP);
    int*      ListTok  = (int*)     (wsb + OFF_LISTTOK);
    int*      ListPr   = (int*)     (wsb + OFF_LISTPR);
    float*    B1eff    = (float*)   (wsb + OFF_B1EFF);
    float*    PairOut  = (float*)   (wsb + OFF_PAIROUT);
    _Float16* W1T      = (_Float16*)(wsb + OFF_W1T);
    _Float16* W2T      = (_Float16*)(wsb + OFF_W2T);

    hipMemsetAsync(wsb, 0, 256, stream);

    k_wconv2<<<1024, 256, 0, stream>>>(ew1, W1T, 512, 1024);
    k_wconv2<<<1024, 256, 0, stream>>>(ew2, W2T, 1024, 512);

    k_router<<<512, 256, 0, stream>>>(
        x, r0_w1,r0_b1,r0_g,r0_be,r0_w2,r0_b2,
           r1_w1,r1_b1,r1_g,r1_be,r1_w2,r1_b2,
           r2_w1,r2_b1,r2_g,r2_be,r2_w2,r2_b2,
        cw1,cb1,cw2,cb2, gw,gb, ent,
        rwp, Wgt, SelExp, ListTok, ListPr, counters, confsum);

    k_b1eff<<<256, 128, 0, stream>>>(emb, ew1, eb1, B1eff);

    hipFuncSetAttribute((const void*)k_expert_mfma,
                        hipFuncAttributeMaxDynamicSharedMemorySize, 131072);
    k_expert_mfma<<<1024, 512, 131072, stream>>>(
        x, W1T, W2T, B1eff, Wgt, ListTok, ListPr, counters, PairOut);

    k_combine<<<T_, 128, 0, stream>>>(
        x, PairOut, Wgt, SelExp, eb2, rgw, rgb, lng, lnb, outp);

    k_aux<<<1, 256, 0, stream>>>(rwp, confsum, auxp);
}